// Round 5
// baseline (22993.845 us; speedup 1.0000x reference)
//
#include <hip/hip_runtime.h>
#include <cmath>

#define LEAK 0.95f
#define ILEAK 0.05f

typedef float f4 __attribute__((ext_vector_type(4)));

// ---------------- Phase 1: u = x @ W_in^T (fp32 tiled GEMM) ----------------
__global__ __launch_bounds__(256) void resv_gemm_uin(
    const float* __restrict__ A, const float* __restrict__ Bm,
    float* __restrict__ C, int M, int N, int K)
{
    __shared__ float As[16][68];
    __shared__ float Bs[16][68];
    const int tid = threadIdx.x;
    const int m0 = blockIdx.y * 64;
    const int n0 = blockIdx.x * 64;
    const int lm = tid >> 2;
    const int lk = (tid & 3) * 4;
    const int ty = tid >> 4;
    const int tx = tid & 15;

    float acc[4][4];
#pragma unroll
    for (int i = 0; i < 4; ++i)
#pragma unroll
        for (int j = 0; j < 4; ++j) acc[i][j] = 0.f;

    const float* Aptr = A + (size_t)(m0 + lm) * K + lk;
    const float* Bptr = Bm + (size_t)(n0 + lm) * K + lk;

    for (int k0 = 0; k0 < K; k0 += 16) {
        float4 av = *(const float4*)(Aptr + k0);
        float4 bv = *(const float4*)(Bptr + k0);
        __syncthreads();
        As[lk + 0][lm] = av.x; As[lk + 1][lm] = av.y;
        As[lk + 2][lm] = av.z; As[lk + 3][lm] = av.w;
        Bs[lk + 0][lm] = bv.x; Bs[lk + 1][lm] = bv.y;
        Bs[lk + 2][lm] = bv.z; Bs[lk + 3][lm] = bv.w;
        __syncthreads();
#pragma unroll
        for (int kk = 0; kk < 16; ++kk) {
            float4 a = *(const float4*)(&As[kk][ty * 4]);
            float4 b = *(const float4*)(&Bs[kk][tx * 4]);
            acc[0][0] += a.x * b.x; acc[0][1] += a.x * b.y; acc[0][2] += a.x * b.z; acc[0][3] += a.x * b.w;
            acc[1][0] += a.y * b.x; acc[1][1] += a.y * b.y; acc[1][2] += a.y * b.z; acc[1][3] += a.y * b.w;
            acc[2][0] += a.z * b.x; acc[2][1] += a.z * b.y; acc[2][2] += a.z * b.z; acc[2][3] += a.z * b.w;
            acc[3][0] += a.w * b.x; acc[3][1] += a.w * b.y; acc[3][2] += a.w * b.z; acc[3][3] += a.w * b.w;
        }
    }
    float* Cp = C + (size_t)(m0 + ty * 4) * N + n0 + tx * 4;
#pragma unroll
    for (int i = 0; i < 4; ++i) {
        float4 v = make_float4(acc[i][0], acc[i][1], acc[i][2], acc[i][3]);
        *(float4*)(Cp + (size_t)i * N) = v;
    }
}

// ---------------- Phase 2: reservoir recurrence (agent-scope sync) --------
// 256 wgs, 96KB dynamic LDS pins 1 wg/CU (co-residency proven r1/r2/r4).
// group g = bid&7 owns batches 4g..4g+3; row-wg r = bid>>3 owns rows 32r..+31.
// W_res slice in REGISTERS (32 x f4/lane). States in [slot][g][b][h] layout:
// every 128B line written whole by 32 consecutive lanes of wave 0 (full-line
// write-through; fixes r4's WRITE amplification). prev staged b-major in LDS,
// compute reads are 2-addr broadcasts. Sync: per-wg monotone flag words
// (relaxed agent store/load only, r2-proven), poll with s_sleep backoff.
// Finish is wave0-only (pv kept in registers), drains own vmcnt, stores flag
// -- no third barrier; waves 1-3 head straight to the next poll.
__global__ __launch_bounds__(256, 1) void resv_recur(
    const float* __restrict__ Wres,   // [1024][1024]
    float* __restrict__ out,          // [32][2048][1024] (pre-filled with u)
    float* __restrict__ states,       // ws: [2 slots][8 g][4 b][1024 h] floats
    unsigned* __restrict__ flags)     // ws: [8 g][32 wg] (one 128B line/group)
{
    constexpr int H = 1024, S = 2048;
    extern __shared__ float sm[];
    float* prevL = sm;                 // [4][1024] b-major (16 KB)
    float* uL    = sm + 4096;          // [2][2048] double-buffered u (16 KB)
    float* red   = sm + 8192;          // [4 q][32 row] f4-over-b (2 KB)

    const int tid = threadIdx.x;
    const int g  = blockIdx.x & 7;
    const int r  = blockIdx.x >> 3;
    const int h0 = r * 32;
    const int b0 = g * 4;

    const int w   = tid >> 6;          // wave = k-quarter
    const int l   = tid & 63;
    const int lh  = l >> 5;            // k-half within quarter
    const int row = l & 31;            // row within this wg's 32-row block
    const int K0  = w * 256 + lh * 128;
    const int kb  = K0 >> 2;           // f4 index base

    // ---- one-time: W_res[h0+row][K0 .. K0+127] into 32 f4 registers ----
    f4 Wreg[32];
    {
        const f4* wsrc = (const f4*)(Wres + (size_t)(h0 + row) * H + K0);
#pragma unroll
        for (int i = 0; i < 32; ++i) Wreg[i] = wsrc[i];
    }

    unsigned* flagLine = flags + g * 32;
    float pv0 = 0.f, pv1 = 0.f;        // wave0: this lane's 2 previous outputs

    for (int t = 0; t < S; ++t) {
        // ---- stage u[t..t+15] into double buffer (plain loads, private) ----
        if ((t & 15) == 0) {
            float* uB = uL + ((t >> 4) & 1) * 2048;
            for (int c = tid; c < 512; c += 256) {
                int rw4 = c & 7, b = (c >> 3) & 3, tt = c >> 5;
                const float4* src =
                    (const float4*)(out + ((size_t)(b0 + b) * S + (t + tt)) * H + h0);
                ((float4*)uB)[(tt * 4 + b) * 8 + rw4] = src[rw4];
            }
        }
        // ---- wait for all 32 wgs of this group to publish states(t) ----
        if (t) {
            const unsigned tgt = (unsigned)t;
            unsigned fv = __hip_atomic_load(flagLine + (tid & 31), __ATOMIC_RELAXED,
                                            __HIP_MEMORY_SCOPE_AGENT);
            while (__any((int)(fv < tgt))) {
                __builtin_amdgcn_s_sleep(2);   // backoff: ~128cy between attempts
                fv = __hip_atomic_load(flagLine + (tid & 31), __ATOMIC_RELAXED,
                                       __HIP_MEMORY_SCOPE_AGENT);
            }
            __builtin_amdgcn_sched_barrier(0);
        }
        // ---- stage prev[4][1024] b-major; wave w loads k-quarter w ----
        {
            const unsigned long long* src =
                (const unsigned long long*)(states + (size_t)((t & 1) * 8 + g) * 4096);
            unsigned long long* dst = (unsigned long long*)prevL;
#pragma unroll
            for (int c = 0; c < 8; ++c) {
                int idx = (c >> 1) * 512 + w * 128 + (c & 1) * 64 + l;  // 8B units
                dst[idx] = __hip_atomic_load(src + idx, __ATOMIC_RELAXED,
                                             __HIP_MEMORY_SCOPE_AGENT);
            }
        }
        __syncthreads();

        // ---- compute: acc[b] = sum_k W[row][k]*prev[b][k] (broadcast f4s) ----
        float a0 = 0.f, a1 = 0.f, a2 = 0.f, a3 = 0.f;
        const f4* P = (const f4*)prevL;
#pragma unroll
        for (int i = 0; i < 32; ++i) {
            f4 wv = Wreg[i];
            f4 p0 = P[kb + i];
            f4 p1 = P[256 + kb + i];
            f4 p2 = P[512 + kb + i];
            f4 p3 = P[768 + kb + i];
            a0 += wv.x * p0.x + wv.y * p0.y + wv.z * p0.z + wv.w * p0.w;
            a1 += wv.x * p1.x + wv.y * p1.y + wv.z * p1.z + wv.w * p1.w;
            a2 += wv.x * p2.x + wv.y * p2.y + wv.z * p2.z + wv.w * p2.w;
            a3 += wv.x * p3.x + wv.y * p3.y + wv.z * p3.z + wv.w * p3.w;
        }
        // combine the two k-halves (lanes l and l^32 share a row)
        a0 += __shfl_xor(a0, 32, 64);
        a1 += __shfl_xor(a1, 32, 64);
        a2 += __shfl_xor(a2, 32, 64);
        a3 += __shfl_xor(a3, 32, 64);
        if (l < 32) {
            f4 v; v.x = a0; v.y = a1; v.z = a2; v.w = a3;
            ((f4*)red)[w * 32 + row] = v;
        }
        __syncthreads();

        // ---- finish (wave 0 only): 2 outputs/lane; full-line state stores ----
        if (w == 0) {
            float* uB = uL + ((t >> 4) & 1) * 2048;
            float* st = states + (size_t)(((t + 1) & 1) * 8 + g) * 4096;
#pragma unroll
            for (int s = 0; s < 2; ++s) {
                int o  = l + (s << 6);
                int fb = o >> 5, frw = o & 31;
                float sum = red[(0 * 32 + frw) * 4 + fb] + red[(1 * 32 + frw) * 4 + fb]
                          + red[(2 * 32 + frw) * 4 + fb] + red[(3 * 32 + frw) * 4 + fb];
                float uv = uB[((t & 15) * 4 + fb) * 32 + frw];
                float pv = s ? pv1 : pv0;
                float ns = LEAK * tanhf(uv + sum) + ILEAK * pv;
                if (s) pv1 = ns; else pv0 = ns;
                __hip_atomic_store(st + fb * H + h0 + frw, ns,
                                   __ATOMIC_RELAXED, __HIP_MEMORY_SCOPE_AGENT);
                out[((size_t)(b0 + fb) * S + t) * H + h0 + frw] = ns;
            }
            asm volatile("s_waitcnt vmcnt(0)" ::: "memory");  // states at agent CP
            if (l == 0 && t < S - 1) {
                __hip_atomic_store(flagLine + r, (unsigned)(t + 1),
                                   __ATOMIC_RELAXED, __HIP_MEMORY_SCOPE_AGENT);
            }
        }
        // no barrier: waves 1-3 proceed to next poll; they cannot pass it
        // until our own flag (stored above) reaches t+1.
    }
}

extern "C" void kernel_launch(void* const* d_in, const int* in_sizes, int n_in,
                              void* d_out, int out_size, void* d_ws, size_t ws_size,
                              hipStream_t stream)
{
    const float* x    = (const float*)d_in[0];   // [32][2048][512]
    const float* Win  = (const float*)d_in[1];   // [1024][512]
    const float* Wres = (const float*)d_in[2];   // [1024][1024]
    float* out = (float*)d_out;                  // [32][2048][1024]

    float*    states = (float*)d_ws;                          // 262144 B
    unsigned* flags  = (unsigned*)((char*)d_ws + 262144);     // 1024 B

    // zero states (t=0 prev) and flags every launch (graph-replay safe)
    hipMemsetAsync(d_ws, 0, 262144 + 1024, stream);

    // phase 1: u = x @ W_in^T into d_out
    dim3 gemm_grid(1024 / 64, 65536 / 64);
    resv_gemm_uin<<<gemm_grid, 256, 0, stream>>>(x, Win, out, 65536, 1024, 512);

    // phase 2: recurrence. 96KB dynamic LDS pins exactly 1 wg/CU.
    constexpr int kLds = 96 * 1024;
    hipFuncSetAttribute((const void*)resv_recur,
                        hipFuncAttributeMaxDynamicSharedMemorySize, kLds);
    resv_recur<<<dim3(256), dim3(256), kLds, stream>>>(Wres, out, states, flags);
}

// Round 6
// 14607.985 us; speedup vs baseline: 1.5741x; 1.5741x over previous
//
#include <hip/hip_runtime.h>
#include <cmath>

#define LEAK 0.95f
#define ILEAK 0.05f

typedef float f4 __attribute__((ext_vector_type(4)));

// ---------------- Phase 1: u = x @ W_in^T (fp32 tiled GEMM) ----------------
__global__ __launch_bounds__(256) void resv_gemm_uin(
    const float* __restrict__ A, const float* __restrict__ Bm,
    float* __restrict__ C, int M, int N, int K)
{
    __shared__ float As[16][68];
    __shared__ float Bs[16][68];
    const int tid = threadIdx.x;
    const int m0 = blockIdx.y * 64;
    const int n0 = blockIdx.x * 64;
    const int lm = tid >> 2;
    const int lk = (tid & 3) * 4;
    const int ty = tid >> 4;
    const int tx = tid & 15;

    float acc[4][4];
#pragma unroll
    for (int i = 0; i < 4; ++i)
#pragma unroll
        for (int j = 0; j < 4; ++j) acc[i][j] = 0.f;

    const float* Aptr = A + (size_t)(m0 + lm) * K + lk;
    const float* Bptr = Bm + (size_t)(n0 + lm) * K + lk;

    for (int k0 = 0; k0 < K; k0 += 16) {
        float4 av = *(const float4*)(Aptr + k0);
        float4 bv = *(const float4*)(Bptr + k0);
        __syncthreads();
        As[lk + 0][lm] = av.x; As[lk + 1][lm] = av.y;
        As[lk + 2][lm] = av.z; As[lk + 3][lm] = av.w;
        Bs[lk + 0][lm] = bv.x; Bs[lk + 1][lm] = bv.y;
        Bs[lk + 2][lm] = bv.z; Bs[lk + 3][lm] = bv.w;
        __syncthreads();
#pragma unroll
        for (int kk = 0; kk < 16; ++kk) {
            float4 a = *(const float4*)(&As[kk][ty * 4]);
            float4 b = *(const float4*)(&Bs[kk][tx * 4]);
            acc[0][0] += a.x * b.x; acc[0][1] += a.x * b.y; acc[0][2] += a.x * b.z; acc[0][3] += a.x * b.w;
            acc[1][0] += a.y * b.x; acc[1][1] += a.y * b.y; acc[1][2] += a.y * b.z; acc[1][3] += a.y * b.w;
            acc[2][0] += a.z * b.x; acc[2][1] += a.z * b.y; acc[2][2] += a.z * b.z; acc[2][3] += a.z * b.w;
            acc[3][0] += a.w * b.x; acc[3][1] += a.w * b.y; acc[3][2] += a.w * b.z; acc[3][3] += a.w * b.w;
        }
    }
    float* Cp = C + (size_t)(m0 + ty * 4) * N + n0 + tx * 4;
#pragma unroll
    for (int i = 0; i < 4; ++i) {
        float4 v = make_float4(acc[i][0], acc[i][1], acc[i][2], acc[i][3]);
        *(float4*)(Cp + (size_t)i * N) = v;
    }
}

// ---------------- Phase 2: reservoir recurrence --------------------------
// EXACT round-2 sync skeleton (proven fastest): group g=bid&7 owns batches
// 4g..4g+3; row-wg r=bid>>3 owns rows 32r..32r+31. states [slot][32 b][1024 h]
// (full-line agent stores), per-group hot COUNTER advanced by fetch_add,
// tid0 polls the single word, __syncthreads releases. All cross-wg data via
// relaxed agent-scope atomics only (no fences).
// ONLY change vs r2: compute core uses register-resident W (32 f4/lane) with
// 2-address broadcast ds_read_b128 prev reads (r5-verified numerics), and the
// 16-step u-stage is hoisted between drain-barrier and poll (publish early).
__global__ __launch_bounds__(256, 1) void resv_recur(
    const float* __restrict__ Wres,   // [1024][1024]
    float* __restrict__ out,          // [32][2048][1024] (pre-filled with u)
    float* __restrict__ states,       // ws: [2 slots][32 b][1024 h] floats
    unsigned* __restrict__ cnt)       // ws: [8 groups] padded to 256B each
{
    constexpr int H = 1024, S = 2048;
    extern __shared__ float sm[];
    float* prevL = sm;                 // [4][1024] b-major (16 KB)
    float* uL    = sm + 4096;          // [2][2048] double-buffered u (16 KB)
    float* red   = sm + 8192;          // [4 q][32 row] f4-over-b (2 KB)

    const int tid = threadIdx.x;
    const int g  = blockIdx.x & 7;
    const int r  = blockIdx.x >> 3;
    const int h0 = r * 32;
    const int b0 = g * 4;

    const int w   = tid >> 6;          // wave = k-quarter
    const int l   = tid & 63;
    const int lh  = l >> 5;            // k-half within quarter
    const int row = l & 31;            // row within this wg's 32-row block
    const int K0  = w * 256 + lh * 128;
    const int kb  = K0 >> 2;           // f4 index base

    // ---- one-time: W_res[h0+row][K0 .. K0+127] into 32 f4 registers ----
    f4 Wreg[32];
    {
        const f4* wsrc = (const f4*)(Wres + (size_t)(h0 + row) * H + K0);
#pragma unroll
        for (int i = 0; i < 32; ++i) Wreg[i] = wsrc[i];
    }

    const int fb  = tid >> 5;          // finish: batch (tid<128)
    const int frw = tid & 31;          // finish: row

    unsigned* flag = cnt + (size_t)g * 64;   // 256B-padded per-group counter

    // prologue: stage u[0..15] into buffer 0
    {
        float* uB = uL;
        for (int c = tid; c < 512; c += 256) {
            int rw4 = c & 7, b = (c >> 3) & 3, tt = c >> 5;
            const float4* src =
                (const float4*)(out + ((size_t)(b0 + b) * S + tt) * H + h0);
            ((float4*)uB)[(tt * 4 + b) * 8 + rw4] = src[rw4];
        }
    }

    for (int t = 0; t < S; ++t) {
        // ---- stage prev[4][1024] b-major via agent-scope atomic loads ----
        {
            const unsigned long long* src =
                (const unsigned long long*)(states + (size_t)(t & 1) * 32 * H + (size_t)b0 * H);
            unsigned long long* dst = (unsigned long long*)prevL;
#pragma unroll
            for (int c = 0; c < 8; ++c) {
                dst[tid + c * 256] = __hip_atomic_load(src + tid + c * 256,
                                                       __ATOMIC_RELAXED,
                                                       __HIP_MEMORY_SCOPE_AGENT);
            }
        }
        __syncthreads();

        // ---- compute: acc[b] = sum_k W[row][k]*prev[b][k] (broadcast f4s) ----
        float a0 = 0.f, a1 = 0.f, a2 = 0.f, a3 = 0.f;
        const f4* P = (const f4*)prevL;
#pragma unroll
        for (int i = 0; i < 32; ++i) {
            f4 wv = Wreg[i];
            f4 p0 = P[kb + i];
            f4 p1 = P[256 + kb + i];
            f4 p2 = P[512 + kb + i];
            f4 p3 = P[768 + kb + i];
            a0 += wv.x * p0.x + wv.y * p0.y + wv.z * p0.z + wv.w * p0.w;
            a1 += wv.x * p1.x + wv.y * p1.y + wv.z * p1.z + wv.w * p1.w;
            a2 += wv.x * p2.x + wv.y * p2.y + wv.z * p2.z + wv.w * p2.w;
            a3 += wv.x * p3.x + wv.y * p3.y + wv.z * p3.z + wv.w * p3.w;
        }
        // combine the two k-halves (lanes l and l^32 share a row)
        a0 += __shfl_xor(a0, 32, 64);
        a1 += __shfl_xor(a1, 32, 64);
        a2 += __shfl_xor(a2, 32, 64);
        a3 += __shfl_xor(a3, 32, 64);
        if (l < 32) {
            f4 v; v.x = a0; v.y = a1; v.z = a2; v.w = a3;
            ((f4*)red)[w * 32 + row] = v;
        }
        __syncthreads();

        // ---- finish (tid<128): sum quarters, tanh, leak, publish ----
        if (tid < 128) {
            float sum = red[(0 * 32 + frw) * 4 + fb] + red[(1 * 32 + frw) * 4 + fb]
                      + red[(2 * 32 + frw) * 4 + fb] + red[(3 * 32 + frw) * 4 + fb];
            float uv = uL[((t >> 4) & 1) * 2048 + (((t & 15) * 4 + fb) << 5) + frw];
            float pv = prevL[(fb << 10) + h0 + frw];
            float ns = LEAK * tanhf(uv + sum) + ILEAK * pv;
            __hip_atomic_store(
                states + (size_t)((t + 1) & 1) * 32 * H + (size_t)(b0 + fb) * H + h0 + frw,
                ns, __ATOMIC_RELAXED, __HIP_MEMORY_SCOPE_AGENT);
            out[((size_t)(b0 + fb) * S + t) * H + h0 + frw] = ns;
        }
        asm volatile("s_waitcnt vmcnt(0)" ::: "memory");  // drain before barrier
        __syncthreads();                                  // states(t+1) at agent CP

        if (t < S - 1) {
            // publish as early as possible
            if (tid == 0)
                __hip_atomic_fetch_add(flag, 1u, __ATOMIC_RELAXED,
                                       __HIP_MEMORY_SCOPE_AGENT);
            // overlap the next u-block stage with other wgs' publishes
            if (((t + 1) & 15) == 0) {
                float* uB = uL + (((t + 1) >> 4) & 1) * 2048;
                for (int c = tid; c < 512; c += 256) {
                    int rw4 = c & 7, b = (c >> 3) & 3, tt = c >> 5;
                    const float4* src =
                        (const float4*)(out + ((size_t)(b0 + b) * S + (t + 1 + tt)) * H + h0);
                    ((float4*)uB)[(tt * 4 + b) * 8 + rw4] = src[rw4];
                }
            }
            if (tid == 0) {
                const unsigned target = 32u * (unsigned)(t + 1);
                while (__hip_atomic_load(flag, __ATOMIC_RELAXED,
                                         __HIP_MEMORY_SCOPE_AGENT) < target) {}
            }
            __syncthreads();
        }
    }
}

extern "C" void kernel_launch(void* const* d_in, const int* in_sizes, int n_in,
                              void* d_out, int out_size, void* d_ws, size_t ws_size,
                              hipStream_t stream)
{
    const float* x    = (const float*)d_in[0];   // [32][2048][512]
    const float* Win  = (const float*)d_in[1];   // [1024][512]
    const float* Wres = (const float*)d_in[2];   // [1024][1024]
    float* out = (float*)d_out;                  // [32][2048][1024]

    float*    states = (float*)d_ws;                          // 262144 B
    unsigned* cnt    = (unsigned*)((char*)d_ws + 262144);     // 8 x 256 B

    // zero states (t=0 prev) and counters every launch (graph-replay safe)
    hipMemsetAsync(d_ws, 0, 262144 + 2048, stream);

    // phase 1: u = x @ W_in^T into d_out
    dim3 gemm_grid(1024 / 64, 65536 / 64);
    resv_gemm_uin<<<gemm_grid, 256, 0, stream>>>(x, Win, out, 65536, 1024, 512);

    // phase 2: recurrence. 96KB dynamic LDS pins exactly 1 wg/CU
    // (co-residency of all 256 wgs proven rounds 1-5).
    constexpr int kLds = 96 * 1024;
    hipFuncSetAttribute((const void*)resv_recur,
                        hipFuncAttributeMaxDynamicSharedMemorySize, kLds);
    resv_recur<<<dim3(256), dim3(256), kLds, stream>>>(Wres, out, states, cnt);
}

// Round 7
// 11595.623 us; speedup vs baseline: 1.9830x; 1.2598x over previous
//
#include <hip/hip_runtime.h>
#include <cmath>

#define LEAK 0.95f
#define ILEAK 0.05f

typedef float f4 __attribute__((ext_vector_type(4)));
typedef unsigned long long ull;

// ---------------- Phase 1: u = x @ W_in^T (fp32 tiled GEMM) ----------------
__global__ __launch_bounds__(256) void resv_gemm_uin(
    const float* __restrict__ A, const float* __restrict__ Bm,
    float* __restrict__ C, int M, int N, int K)
{
    __shared__ float As[16][68];
    __shared__ float Bs[16][68];
    const int tid = threadIdx.x;
    const int m0 = blockIdx.y * 64;
    const int n0 = blockIdx.x * 64;
    const int lm = tid >> 2;
    const int lk = (tid & 3) * 4;
    const int ty = tid >> 4;
    const int tx = tid & 15;

    float acc[4][4];
#pragma unroll
    for (int i = 0; i < 4; ++i)
#pragma unroll
        for (int j = 0; j < 4; ++j) acc[i][j] = 0.f;

    const float* Aptr = A + (size_t)(m0 + lm) * K + lk;
    const float* Bptr = Bm + (size_t)(n0 + lm) * K + lk;

    for (int k0 = 0; k0 < K; k0 += 16) {
        float4 av = *(const float4*)(Aptr + k0);
        float4 bv = *(const float4*)(Bptr + k0);
        __syncthreads();
        As[lk + 0][lm] = av.x; As[lk + 1][lm] = av.y;
        As[lk + 2][lm] = av.z; As[lk + 3][lm] = av.w;
        Bs[lk + 0][lm] = bv.x; Bs[lk + 1][lm] = bv.y;
        Bs[lk + 2][lm] = bv.z; Bs[lk + 3][lm] = bv.w;
        __syncthreads();
#pragma unroll
        for (int kk = 0; kk < 16; ++kk) {
            float4 a = *(const float4*)(&As[kk][ty * 4]);
            float4 b = *(const float4*)(&Bs[kk][tx * 4]);
            acc[0][0] += a.x * b.x; acc[0][1] += a.x * b.y; acc[0][2] += a.x * b.z; acc[0][3] += a.x * b.w;
            acc[1][0] += a.y * b.x; acc[1][1] += a.y * b.y; acc[1][2] += a.y * b.z; acc[1][3] += a.y * b.w;
            acc[2][0] += a.z * b.x; acc[2][1] += a.z * b.y; acc[2][2] += a.z * b.z; acc[2][3] += a.z * b.w;
            acc[3][0] += a.w * b.x; acc[3][1] += a.w * b.y; acc[3][2] += a.w * b.z; acc[3][3] += a.w * b.w;
        }
    }
    float* Cp = C + (size_t)(m0 + ty * 4) * N + n0 + tx * 4;
#pragma unroll
    for (int i = 0; i < 4; ++i) {
        float4 v = make_float4(acc[i][0], acc[i][1], acc[i][2], acc[i][3]);
        *(float4*)(Cp + (size_t)i * N) = v;
    }
}

// ---------------- Phase 2: reservoir recurrence, data-tagged sync ---------
// 256 wgs, 96KB dynamic LDS pins 1 wg/CU (co-residency proven r1-r6).
// group g = bid&7 owns batches 4g..4g+3; row-wg r = bid>>3 owns rows 32r..+31.
// States are packed 8B pairs (tag<<32 | float bits), tag = consuming step.
// Consumers POLL THE DATA: load all 16 pairs, check tags == t, retry. No
// flags, no fetch_add, no producer-side drain. 2-slot ping-pong is safe by
// the all-to-all dependency induction (tag t+2 can't appear in a slot until
// every wg finished consuming tag t). memset-0 = (tag 0, 0.0f) = step-0 init.
// All pair accesses are relaxed agent-scope 8B atomics (r2-proven coherent,
// single-copy atomic -> no val/tag tearing).
__global__ __launch_bounds__(256, 1) void resv_recur(
    const float* __restrict__ Wres,   // [1024][1024]
    float* __restrict__ out,          // [32][2048][1024] (pre-filled with u)
    ull* __restrict__ pairs)          // ws: [2 slots][32 b][1024 h] 8B pairs
{
    constexpr int H = 1024, S = 2048;
    extern __shared__ float sm[];
    float* prevL = sm;                 // [4][1024] b-major (16 KB)
    float* uL    = sm + 4096;          // [2][2048] double-buffered u (16 KB)
    float* red   = sm + 8192;          // [4 q][32 row] f4-over-b (2 KB)

    const int tid = threadIdx.x;
    const int g  = blockIdx.x & 7;
    const int r  = blockIdx.x >> 3;
    const int h0 = r * 32;
    const int b0 = g * 4;

    const int w   = tid >> 6;          // wave = k-quarter
    const int l   = tid & 63;
    const int lh  = l >> 5;            // k-half within quarter
    const int row = l & 31;            // row within this wg's 32-row block
    const int K0  = w * 256 + lh * 128;
    const int kb  = K0 >> 2;           // f4 index base

    // ---- one-time: W_res[h0+row][K0 .. K0+127] into 32 f4 registers ----
    f4 Wreg[32];
    {
        const f4* wsrc = (const f4*)(Wres + (size_t)(h0 + row) * H + K0);
#pragma unroll
        for (int i = 0; i < 32; ++i) Wreg[i] = wsrc[i];
    }

    const int fb  = tid >> 5;          // finish: batch (tid<128)
    const int frw = tid & 31;          // finish: row
    float pv = 0.f;                    // tid<128: own element's previous value

    for (int t = 0; t < S; ++t) {
        // ---- stage u[t..t+15] into double buffer (own region, plain) ----
        if ((t & 15) == 0) {
            float* uB = uL + ((t >> 4) & 1) * 2048;
            for (int c = tid; c < 512; c += 256) {
                int rw4 = c & 7, b = (c >> 3) & 3, tt = c >> 5;
                const float4* src =
                    (const float4*)(out + ((size_t)(b0 + b) * S + (t + tt)) * H + h0);
                ((float4*)uB)[(tt * 4 + b) * 8 + rw4] = src[rw4];
            }
        }
        // ---- poll-load prev: 16 pairs/lane, retry until all tags == t ----
        {
            const ull* src = pairs + ((size_t)(t & 1) * 32 + b0) * 1024;
            ull v[16];
            const unsigned tgt = (unsigned)t;
            for (;;) {
#pragma unroll
                for (int c = 0; c < 16; ++c)
                    v[c] = __hip_atomic_load(src + c * 256 + tid, __ATOMIC_RELAXED,
                                             __HIP_MEMORY_SCOPE_AGENT);
                int ok = 1;
#pragma unroll
                for (int c = 0; c < 16; ++c)
                    ok &= ((unsigned)(v[c] >> 32) == tgt);
                if (__all(ok)) break;
            }
#pragma unroll
            for (int c = 0; c < 16; ++c)
                prevL[c * 256 + tid] = __uint_as_float((unsigned)v[c]);
        }
        __syncthreads();

        // ---- compute: acc[b] = sum_k W[row][k]*prev[b][k] (broadcast f4s) ----
        float a0 = 0.f, a1 = 0.f, a2 = 0.f, a3 = 0.f;
        const f4* P = (const f4*)prevL;
#pragma unroll
        for (int i = 0; i < 32; ++i) {
            f4 wv = Wreg[i];
            f4 p0 = P[kb + i];
            f4 p1 = P[256 + kb + i];
            f4 p2 = P[512 + kb + i];
            f4 p3 = P[768 + kb + i];
            a0 += wv.x * p0.x + wv.y * p0.y + wv.z * p0.z + wv.w * p0.w;
            a1 += wv.x * p1.x + wv.y * p1.y + wv.z * p1.z + wv.w * p1.w;
            a2 += wv.x * p2.x + wv.y * p2.y + wv.z * p2.z + wv.w * p2.w;
            a3 += wv.x * p3.x + wv.y * p3.y + wv.z * p3.z + wv.w * p3.w;
        }
        // combine the two k-halves (lanes l and l^32 share a row)
        a0 += __shfl_xor(a0, 32, 64);
        a1 += __shfl_xor(a1, 32, 64);
        a2 += __shfl_xor(a2, 32, 64);
        a3 += __shfl_xor(a3, 32, 64);
        if (l < 32) {
            f4 v; v.x = a0; v.y = a1; v.z = a2; v.w = a3;
            ((f4*)red)[w * 32 + row] = v;
        }
        __syncthreads();

        // ---- finish (tid<128): 1 element each; publish tagged pair ----
        if (tid < 128) {
            float sum = red[(0 * 32 + frw) * 4 + fb] + red[(1 * 32 + frw) * 4 + fb]
                      + red[(2 * 32 + frw) * 4 + fb] + red[(3 * 32 + frw) * 4 + fb];
            float uv = uL[((t >> 4) & 1) * 2048 + (((t & 15) * 4 + fb) << 5) + frw];
            float ns = LEAK * tanhf(uv + sum) + ILEAK * pv;
            pv = ns;
            ull pk = ((ull)(unsigned)(t + 1) << 32) | (ull)__float_as_uint(ns);
            __hip_atomic_store(
                pairs + ((size_t)((t + 1) & 1) * 32 + b0 + fb) * 1024 + h0 + frw,
                pk, __ATOMIC_RELAXED, __HIP_MEMORY_SCOPE_AGENT);
            out[((size_t)(b0 + fb) * S + t) * H + h0 + frw] = ns;
        }
        // no drain, no flag: consumers poll the tagged data itself.
        // barrier protects red/uL (WAR vs next step) -- prevL WAR is safe
        // because next stage's LDS writes happen after this barrier too.
        __syncthreads();
    }
}

extern "C" void kernel_launch(void* const* d_in, const int* in_sizes, int n_in,
                              void* d_out, int out_size, void* d_ws, size_t ws_size,
                              hipStream_t stream)
{
    const float* x    = (const float*)d_in[0];   // [32][2048][512]
    const float* Win  = (const float*)d_in[1];   // [1024][512]
    const float* Wres = (const float*)d_in[2];   // [1024][1024]
    float* out = (float*)d_out;                  // [32][2048][1024]

    ull* pairs = (ull*)d_ws;                     // 2*32*1024*8 = 524288 B

    // zero pairs every launch: (tag 0, 0.0f) == step-0 initial state
    hipMemsetAsync(d_ws, 0, 524288, stream);

    // phase 1: u = x @ W_in^T into d_out
    dim3 gemm_grid(1024 / 64, 65536 / 64);
    resv_gemm_uin<<<gemm_grid, 256, 0, stream>>>(x, Win, out, 65536, 1024, 512);

    // phase 2: recurrence. 96KB dynamic LDS pins exactly 1 wg/CU
    // (co-residency of all 256 wgs proven rounds 1-6).
    constexpr int kLds = 96 * 1024;
    hipFuncSetAttribute((const void*)resv_recur,
                        hipFuncAttributeMaxDynamicSharedMemorySize, kLds);
    resv_recur<<<dim3(256), dim3(256), kLds, stream>>>(Wres, out, pairs);
}